// Round 8
// baseline (1207.178 us; speedup 1.0000x reference)
//
#include <hip/hip_runtime.h>

#define T_LEN 2048
#define BATCH 512
#define HID   25
#define NNOTES 51
#define EMBED 50
#define G4    100   // 4*HID
#define NBLK  256   // one block serves batch elements b and b+NBLK

typedef float v2f __attribute__((ext_vector_type(2)));

#define REP25(M) M(0) M(1) M(2) M(3) M(4) M(5) M(6) M(7) M(8) M(9) \
  M(10) M(11) M(12) M(13) M(14) M(15) M(16) M(17) M(18) M(19) \
  M(20) M(21) M(22) M(23) M(24)

#define NL2E 1.442695041f   // log2(e)

#if __has_builtin(__builtin_amdgcn_exp2f)
#define EXP2(x) __builtin_amdgcn_exp2f(x)
#else
#define EXP2(x) __expf((x) * 0.6931471805599453f)
#endif

__device__ __forceinline__ float bcastf(float v, int lane) {
  return __int_as_float(__builtin_amdgcn_readlane(__float_as_int(v), lane));
}
__device__ __forceinline__ float rcpf_(float x) { return __builtin_amdgcn_rcpf(x); }
__device__ __forceinline__ v2f mk2(float a, float b) { v2f r; r.x = a; r.y = b; return r; }

// Pin: opaque def so the compiler cannot rematerialize the originating load
// inside the loop (safe at <=50 pinned VGPRs per branch — r2/r4 lesson).
__device__ __forceinline__ void pin2(v2f& v) { asm volatile("" : "+v"(v)); }
__device__ __forceinline__ void pin1(float& v) { asm volatile("" : "+v"(v)); }

// zA carries sigmoid-rows (i or f); zB carries (g or o): lanes<25 need tanh on zB,
// lanes 25-49 need sigmoid. sB/aB/bB are per-lane constants selecting the variant.
__device__ __forceinline__ void gates(float zA, float zB, float& c, float& h,
                                      float sB, float aB, float bB, int paddr) {
  float uA = rcpf_(1.0f + EXP2(zA * (-NL2E)));          // sigmoid(zA)
  float eB = EXP2(zB * sB);
  float uB = rcpf_(1.0f + eB);
  float rB = fmaf(aB, uB, bB);                          // tanh(zB) or sigmoid(zB)
  float sf = __int_as_float(__builtin_amdgcn_ds_bpermute(paddr, __float_as_int(uA)));
  float so = __int_as_float(__builtin_amdgcn_ds_bpermute(paddr, __float_as_int(rB)));
  float cn = fmaf(sf, c, uA * rB);
  c = cn;
  float th = fmaf(2.0f, rcpf_(1.0f + EXP2(cn * (-2.0f * NL2E))), -1.0f);
  h = so * th;
}

// Kernel 1: proj[n][j] = bih0[j] + bhh0[j] + sum_e Wih0[j,e]*emb[n,e]
__global__ void build_proj(const float* __restrict__ emb,
                           const float* __restrict__ Wih0,
                           const float* __restrict__ bih0,
                           const float* __restrict__ bhh0,
                           float* __restrict__ proj) {
  const int n = blockIdx.x;
  const int j = threadIdx.x;
  if (j < G4) {
    float acc = bih0[j] + bhh0[j];
    #pragma unroll
    for (int e = 0; e < EMBED; ++e)
      acc = fmaf(Wih0[j * EMBED + e], emb[n * EMBED + e], acc);
    proj[n * G4 + j] = acc;
  }
}

// Kernel 2: one block (4 waves) serves TWO batch elements (b, b+256) through
// the same 4-stage wave-specialized pipeline as r4 (barrier skeleton identical,
// hardware-proven: 2052 barriers/wave, skews 0/1/2/3, depth-2 rings).
// Each stage wave interleaves the two elements' INDEPENDENT chains — stalls in
// one chain (bpermute/exp/rcp latency) are filled by the other chain's issue.
// Weights are shared across elements (no extra weight VGPRs); grid halves to
// 256 -> 1 block/CU, 1 wave/SIMD; each barrier covers 2 element-steps.
//   S0: layer-0 recurrence (Whh0)            -> h0Ring[elem]
//   S1: u = b1 + Wih1 @ h0 (Wih1)            -> uRing[elem]
//   S2: layer-1 recurrence (Whh1)            -> h1Ring[elem]
//   S3: FC head + global stores (fcW)
__global__ __launch_bounds__(256, 1)
void lstm_seq(
    const int* __restrict__ x, const float* __restrict__ proj,
    const float* __restrict__ Whh0,
    const float* __restrict__ Wih1, const float* __restrict__ Whh1,
    const float* __restrict__ bih1, const float* __restrict__ bhh1,
    const float* __restrict__ fcW, const float* __restrict__ fcb,
    float* __restrict__ out) {
  __shared__ float projL[NNOTES * G4];   // 20400 B
  __shared__ int   xL[2][T_LEN];         // 16384 B : note rows for both elements
  __shared__ float h0Ring[2][2][32];     //   512 B : [elem][slot][lane<25]
  __shared__ v2f   uRing[2][2][64];      //  2048 B : [elem][slot][lane]
  __shared__ float h1Ring[2][2][32];     //   512 B

  const int tid = threadIdx.x;
  const int l   = tid & 63;
  const int w   = __builtin_amdgcn_readfirstlane(tid >> 6);  // provably uniform
  const int b0  = blockIdx.x;
  const int b1  = blockIdx.x + NBLK;

  for (int i = tid; i < NNOTES * G4; i += 256) projL[i] = proj[i];
  for (int i = tid; i < T_LEN; i += 256) {
    xL[0][i] = x[b0 * T_LEN + i];
    xL[1][i] = x[b1 * T_LEN + i];
  }
  __syncthreads();   // barrier #0 (all waves)

  const bool act = (l < 50);
  const bool lo  = (l < 25);
  const int jA = act ? l : 0;
  const int jB = act ? (l + 50) : 0;
  const int paddr = ((l + 25) & 63) << 2;

  const float sB = lo ? (-2.0f * NL2E) : (-NL2E);
  const float aB = lo ? 2.0f : 1.0f;
  const float bB = lo ? -1.0f : 0.0f;

  const size_t baseH = (size_t)BATCH * T_LEN * NNOTES;
  const size_t baseC = baseH + (size_t)2 * BATCH * HID;

  if (w == 0) {
    // -------- S0: layer-0 recurrence, elements A and B (independent) --------
    v2f w0[HID];
#define LDW0(i) w0[i] = act ? mk2(Whh0[jA*HID+(i)], Whh0[jB*HID+(i)]) : mk2(0.f,0.f);
    REP25(LDW0)
#undef LDW0
#define PIN0(i) pin2(w0[i]);
    REP25(PIN0)
#undef PIN0

    float hA = 0.f, cA = 0.f, hB = 0.f, cB = 0.f;
    float hbA[HID], hbB[HID];
#define Z0(i) hbA[i] = 0.0f; hbB[i] = 0.0f;
    REP25(Z0)
#undef Z0

    v2f x0 = mk2(projL[xL[0][0] * G4 + jA], projL[xL[0][0] * G4 + jB]);
    v2f x1 = mk2(projL[xL[1][0] * G4 + jA], projL[xL[1][0] * G4 + jB]);

    for (int t = 0; t < T_LEN; ++t) {
      const v2f x0c = x0, x1c = x1;
      { const int nn = (t + 1) & (T_LEN - 1);
        const int nA = xL[0][nn], nB = xL[1][nn];
        x0 = mk2(projL[nA * G4 + jA], projL[nA * G4 + jB]);
        x1 = mk2(projL[nB * G4 + jA], projL[nB * G4 + jB]); }

      // dual matvec: 8 independent accumulator chains
      v2f zp0 = x0c, zp1 = mk2(0.f,0.f), zp2 = mk2(0.f,0.f), zp3 = mk2(0.f,0.f);
      v2f zq0 = x1c, zq1 = mk2(0.f,0.f), zq2 = mk2(0.f,0.f), zq3 = mk2(0.f,0.f);
#define L0S(i) { const v2f ha = { hbA[i], hbA[i] }; const v2f hb = { hbB[i], hbB[i] }; \
      if      (((i)&3)==0) { zp0 = __builtin_elementwise_fma(w0[i], ha, zp0); \
                             zq0 = __builtin_elementwise_fma(w0[i], hb, zq0); } \
      else if (((i)&3)==1) { zp1 = __builtin_elementwise_fma(w0[i], ha, zp1); \
                             zq1 = __builtin_elementwise_fma(w0[i], hb, zq1); } \
      else if (((i)&3)==2) { zp2 = __builtin_elementwise_fma(w0[i], ha, zp2); \
                             zq2 = __builtin_elementwise_fma(w0[i], hb, zq2); } \
      else                 { zp3 = __builtin_elementwise_fma(w0[i], ha, zp3); \
                             zq3 = __builtin_elementwise_fma(w0[i], hb, zq3); } }
      REP25(L0S)
#undef L0S
      const v2f zA = (zp0 + zp1) + (zp2 + zp3);
      const v2f zB = (zq0 + zq1) + (zq2 + zq3);
      // two independent gates: B's ops fill A's bpermute/exp latency
      gates(zA.x, zA.y, cA, hA, sB, aB, bB, paddr);
      gates(zB.x, zB.y, cB, hB, sB, aB, bB, paddr);
#define BC0(i) hbA[i] = bcastf(hA, i); hbB[i] = bcastf(hB, i);
      REP25(BC0)
#undef BC0
      if (lo) { h0Ring[0][t & 1][l] = hA; h0Ring[1][t & 1][l] = hB; }
      __syncthreads();                    // barrier t+1
    }
    __syncthreads();                      // T+1
    __syncthreads();                      // T+2
    __syncthreads();                      // T+3
    if (l < HID) {
      out[baseH + (size_t)b0 * HID + l] = hA;
      out[baseH + (size_t)b1 * HID + l] = hB;
      out[baseC + (size_t)b0 * HID + l] = cA;
      out[baseC + (size_t)b1 * HID + l] = cB;
    }
  } else if (w == 1) {
    // -------- S1: u = b1 + Wih1 @ h0, both elements (independent) --------
    v2f wi1[HID];
#define LDW1(i) wi1[i] = act ? mk2(Wih1[jA*HID+(i)], Wih1[jB*HID+(i)]) : mk2(0.f,0.f);
    REP25(LDW1)
#undef LDW1
    v2f b1v = act ? mk2(bih1[jA] + bhh1[jA], bih1[jB] + bhh1[jB]) : mk2(0.f, 0.f);
#define PIN1(i) pin2(wi1[i]);
    REP25(PIN1)
#undef PIN1
    pin2(b1v);

    __syncthreads();                      // barrier 1 (skew: wait for h0(0))
    for (int t = 0; t < T_LEN; ++t) {
      const float hvA = h0Ring[0][t & 1][lo ? l : 0];
      const float hvB = h0Ring[1][t & 1][lo ? l : 0];
      float hA[HID], hB[HID];
#define BCU(i) hA[i] = bcastf(hvA, i); hB[i] = bcastf(hvB, i);
      REP25(BCU)
#undef BCU
      v2f a0 = b1v, a1 = mk2(0.f,0.f), a2 = mk2(0.f,0.f), a3 = mk2(0.f,0.f);
      v2f c0v = b1v, c1v = mk2(0.f,0.f), c2v = mk2(0.f,0.f), c3v = mk2(0.f,0.f);
#define US(i) { const v2f ha = { hA[i], hA[i] }; const v2f hb = { hB[i], hB[i] }; \
      if      (((i)&3)==0) { a0 = __builtin_elementwise_fma(wi1[i], ha, a0); \
                             c0v = __builtin_elementwise_fma(wi1[i], hb, c0v); } \
      else if (((i)&3)==1) { a1 = __builtin_elementwise_fma(wi1[i], ha, a1); \
                             c1v = __builtin_elementwise_fma(wi1[i], hb, c1v); } \
      else if (((i)&3)==2) { a2 = __builtin_elementwise_fma(wi1[i], ha, a2); \
                             c2v = __builtin_elementwise_fma(wi1[i], hb, c2v); } \
      else                 { a3 = __builtin_elementwise_fma(wi1[i], ha, a3); \
                             c3v = __builtin_elementwise_fma(wi1[i], hb, c3v); } }
      REP25(US)
#undef US
      uRing[0][t & 1][l] = (a0 + a1) + (a2 + a3);
      uRing[1][t & 1][l] = (c0v + c1v) + (c2v + c3v);
      __syncthreads();                    // barrier t+2
    }
    __syncthreads();                      // +1
    __syncthreads();                      // +2
  } else if (w == 2) {
    // -------- S2: layer-1 recurrence, both elements (independent) --------
    v2f wh1[HID];
#define LDW2(i) wh1[i] = act ? mk2(Whh1[jA*HID+(i)], Whh1[jB*HID+(i)]) : mk2(0.f,0.f);
    REP25(LDW2)
#undef LDW2
#define PIN2(i) pin2(wh1[i]);
    REP25(PIN2)
#undef PIN2
    float hA = 0.f, cA = 0.f, hB = 0.f, cB = 0.f;
    float hbA[HID], hbB[HID];
#define Z1(i) hbA[i] = 0.0f; hbB[i] = 0.0f;
    REP25(Z1)
#undef Z1

    __syncthreads();                      // barrier 1
    __syncthreads();                      // barrier 2 (skew: wait for u(0))
    for (int t = 0; t < T_LEN; ++t) {
      const v2f uA = uRing[0][t & 1][l];
      const v2f uB = uRing[1][t & 1][l];
      v2f y0 = mk2(0.f,0.f), y1 = mk2(0.f,0.f), y2 = mk2(0.f,0.f), y3 = mk2(0.f,0.f);
      v2f g0 = mk2(0.f,0.f), g1 = mk2(0.f,0.f), g2 = mk2(0.f,0.f), g3 = mk2(0.f,0.f);
#define L1S(i) { const v2f ha = { hbA[i], hbA[i] }; const v2f hb = { hbB[i], hbB[i] }; \
      if      (((i)&3)==0) { y0 = __builtin_elementwise_fma(wh1[i], ha, y0); \
                             g0 = __builtin_elementwise_fma(wh1[i], hb, g0); } \
      else if (((i)&3)==1) { y1 = __builtin_elementwise_fma(wh1[i], ha, y1); \
                             g1 = __builtin_elementwise_fma(wh1[i], hb, g1); } \
      else if (((i)&3)==2) { y2 = __builtin_elementwise_fma(wh1[i], ha, y2); \
                             g2 = __builtin_elementwise_fma(wh1[i], hb, g2); } \
      else                 { y3 = __builtin_elementwise_fma(wh1[i], ha, y3); \
                             g3 = __builtin_elementwise_fma(wh1[i], hb, g3); } }
      REP25(L1S)
#undef L1S
      const v2f zA = (uA + y0) + (y1 + y2) + y3;
      const v2f zB = (uB + g0) + (g1 + g2) + g3;
      gates(zA.x, zA.y, cA, hA, sB, aB, bB, paddr);
      gates(zB.x, zB.y, cB, hB, sB, aB, bB, paddr);
#define BC1(i) hbA[i] = bcastf(hA, i); hbB[i] = bcastf(hB, i);
      REP25(BC1)
#undef BC1
      if (lo) { h1Ring[0][t & 1][l] = hA; h1Ring[1][t & 1][l] = hB; }
      __syncthreads();                    // barrier t+3
    }
    __syncthreads();                      // +1
    if (l < HID) {
      out[baseH + (size_t)BATCH * HID + (size_t)b0 * HID + l] = hA;
      out[baseH + (size_t)BATCH * HID + (size_t)b1 * HID + l] = hB;
      out[baseC + (size_t)BATCH * HID + (size_t)b0 * HID + l] = cA;
      out[baseC + (size_t)BATCH * HID + (size_t)b1 * HID + l] = cB;
    }
  } else {
    // -------- S3: FC head + stores, both elements (independent) --------
    float fcw[HID];
#define LDF(i) fcw[i] = (l < NNOTES) ? fcW[l*HID+(i)] : 0.0f;
    REP25(LDF)
#undef LDF
#define PINF(i) pin1(fcw[i]);
    REP25(PINF)
#undef PINF
    const float fb = (l < NNOTES) ? fcb[l] : 0.0f;
    float* outrow0 = out + (size_t)b0 * T_LEN * NNOTES;
    float* outrow1 = out + (size_t)b1 * T_LEN * NNOTES;

    __syncthreads();                      // barrier 1
    __syncthreads();                      // barrier 2
    __syncthreads();                      // barrier 3 (skew: wait for h1(0))
    for (int t = 0; t < T_LEN; ++t) {
      const float hvA = h1Ring[0][t & 1][lo ? l : 0];
      const float hvB = h1Ring[1][t & 1][lo ? l : 0];
      float hA[HID], hB[HID];
#define BCF(i) hA[i] = bcastf(hvA, i); hB[i] = bcastf(hvB, i);
      REP25(BCF)
#undef BCF
      float a0 = fb, a1 = 0.f, a2 = 0.f, a3 = 0.f;
      float d0 = fb, d1 = 0.f, d2 = 0.f, d3 = 0.f;
#define FCS(i) { if      (((i)&3)==0) { a0 = fmaf(fcw[i], hA[i], a0); d0 = fmaf(fcw[i], hB[i], d0); } \
                 else if (((i)&3)==1) { a1 = fmaf(fcw[i], hA[i], a1); d1 = fmaf(fcw[i], hB[i], d1); } \
                 else if (((i)&3)==2) { a2 = fmaf(fcw[i], hA[i], a2); d2 = fmaf(fcw[i], hB[i], d2); } \
                 else                 { a3 = fmaf(fcw[i], hA[i], a3); d3 = fmaf(fcw[i], hB[i], d3); } }
      REP25(FCS)
#undef FCS
      if (l < NNOTES) {
        outrow0[t * NNOTES + l] = (a0 + a1) + (a2 + a3);
        outrow1[t * NNOTES + l] = (d0 + d1) + (d2 + d3);
      }
      // raw barrier: rendezvous without draining vmcnt -> store completion
      // latency stays off the pipeline's critical path. The LDS reads above are
      // already consumed (data dep forced lgkmcnt wait); this wave writes no LDS.
      asm volatile("s_barrier" ::: "memory");  // barrier t+4
    }
  }
}

extern "C" void kernel_launch(void* const* d_in, const int* in_sizes, int n_in,
                              void* d_out, int out_size, void* d_ws, size_t ws_size,
                              hipStream_t stream) {
  const int*   x    = (const int*)d_in[0];
  const float* emb  = (const float*)d_in[1];
  const float* Wih0 = (const float*)d_in[2];
  const float* Whh0 = (const float*)d_in[3];
  const float* bih0 = (const float*)d_in[4];
  const float* bhh0 = (const float*)d_in[5];
  const float* Wih1 = (const float*)d_in[6];
  const float* Whh1 = (const float*)d_in[7];
  const float* bih1 = (const float*)d_in[8];
  const float* bhh1 = (const float*)d_in[9];
  const float* fcW  = (const float*)d_in[10];
  const float* fcb  = (const float*)d_in[11];
  float* out  = (float*)d_out;
  float* proj = (float*)d_ws;  // 51*100 floats = 20.4 KB

  build_proj<<<NNOTES, 128, 0, stream>>>(emb, Wih0, bih0, bhh0, proj);
  lstm_seq<<<NBLK, 256, 0, stream>>>(x, proj, Whh0, Wih1, Whh1, bih1, bhh1,
                                     fcW, fcb, out);
}